// Round 2
// baseline (276.601 us; speedup 1.0000x reference)
//
#include <hip/hip_runtime.h>

#define L_FFT 4096
#define NCH 512
#define NROW 8192

typedef __attribute__((ext_vector_type(8))) short bf16x8;
typedef __attribute__((ext_vector_type(4))) float f32x4;

__device__ __forceinline__ void split_bf16(float x, unsigned short& h, unsigned short& l) {
  unsigned u = __float_as_uint(x);
  h = (unsigned short)(u >> 16);                       // truncate -> hi
  float fh = __uint_as_float(u & 0xffff0000u);
  float lo = x - fh;                                   // exact residual
  l = (unsigned short)(__float_as_uint(lo) >> 16);     // truncate -> lo
}

// ---------------------------------------------------------------------------
// K0: bf16 hi/lo trig tables.
// T1h/T1l [k=128][l=4096]: row k<64 = cos(w0*l*index[k]); row 64+k = -sin(...)
// T2h/T2l [l=4096][k=128]: col k<64 = cos(w0*l*k);        col 64+k = +sin(...)
// ---------------------------------------------------------------------------
__global__ __launch_bounds__(256) void k0_tables(const int* __restrict__ index,
                                                 unsigned short* __restrict__ T1h,
                                                 unsigned short* __restrict__ T1l,
                                                 unsigned short* __restrict__ T2h,
                                                 unsigned short* __restrict__ T2l) {
  int idx = blockIdx.x * 256 + threadIdx.x;  // 0..524287
  const float w0 = 6.2831853071795864769f / (float)L_FFT;
  {
    int kk = idx >> 12, l = idx & (L_FFT - 1);
    int f = index[kk & 63];
    int ph = (l * f) & (L_FFT - 1);
    float s, c;
    sincosf(w0 * (float)ph, &s, &c);
    float v = (kk < 64) ? c : -s;
    unsigned short h, lo;
    split_bf16(v, h, lo);
    T1h[idx] = h; T1l[idx] = lo;
  }
  {
    int l2 = idx >> 7, k2 = idx & 127;
    int ph = (l2 * (k2 & 63)) & (L_FFT - 1);
    float s, c;
    sincosf(w0 * (float)ph, &s, &c);
    float v = (k2 < 64) ? c : s;
    unsigned short h, lo;
    split_bf16(v, h, lo);
    T2h[idx] = h; T2l[idx] = lo;
  }
}

// ---------------------------------------------------------------------------
// K1: forward GEMM via MFMA.  part[p][c][k] = sum_l X[c,l]*T1[k,l]
// Block: 4 waves, tile 128c x 128k; wave 64x64 (4x4 of 16x16), K-chunk 32.
// A (X) staged f32 in LDS from q, converted hi/lo in regs; B direct global.
// ---------------------------------------------------------------------------
__global__ __launch_bounds__(256) void k1_forward(const float* __restrict__ q,
                                                  const unsigned short* __restrict__ T1h,
                                                  const unsigned short* __restrict__ T1l,
                                                  float* __restrict__ part,
                                                  int kspan) {
  int ctile = blockIdx.x;            // 0..63
  int p = blockIdx.y;
  int b = ctile >> 2;
  int ch0 = (ctile & 3) * 128;
  int l0base = p * kspan;

  __shared__ float Xs[32][129];      // ~16.5 KB, conflict-free both ways

  int t = threadIdx.x;
  int wave = t >> 6, lane = t & 63;
  int wm = wave >> 1, wn = wave & 1;
  int m16 = lane & 15, kg = lane >> 4;

  f32x4 acc[4][4] = {};              // [mi][ni]

  for (int l0 = l0base; l0 < l0base + kspan; l0 += 32) {
#pragma unroll
    for (int j = 0; j < 16; ++j) {
      int idx = j * 256 + t;
      int lr = idx >> 7, cr = idx & 127;
      Xs[lr][cr] = q[((size_t)b * L_FFT + l0 + lr) * NCH + ch0 + cr];
    }
    __syncthreads();

    // B fragments: rows of T1 (k-cols of G), 8 consecutive l each, L2-hot
    bf16x8 bh[4], bl[4];
#pragma unroll
    for (int ni = 0; ni < 4; ++ni) {
      int kcol = wn * 64 + ni * 16 + m16;
      size_t off = (size_t)kcol * L_FFT + l0 + kg * 8;
      bh[ni] = *(const bf16x8*)(T1h + off);
      bl[ni] = *(const bf16x8*)(T1l + off);
    }

#pragma unroll
    for (int mi = 0; mi < 4; ++mi) {
      int c = wm * 64 + mi * 16 + m16;
      bf16x8 ah, al;
#pragma unroll
      for (int i = 0; i < 8; ++i) {
        float x = Xs[kg * 8 + i][c];
        unsigned short h, lo;
        split_bf16(x, h, lo);
        ah[i] = (short)h; al[i] = (short)lo;
      }
#pragma unroll
      for (int ni = 0; ni < 4; ++ni) {
        acc[mi][ni] = __builtin_amdgcn_mfma_f32_16x16x32_bf16(ah, bh[ni], acc[mi][ni], 0, 0, 0);
        acc[mi][ni] = __builtin_amdgcn_mfma_f32_16x16x32_bf16(ah, bl[ni], acc[mi][ni], 0, 0, 0);
        acc[mi][ni] = __builtin_amdgcn_mfma_f32_16x16x32_bf16(al, bh[ni], acc[mi][ni], 0, 0, 0);
      }
    }
    __syncthreads();
  }

  int base_c = ctile * 128 + wm * 64;
  float* dst = part + (size_t)p * 1048576;
#pragma unroll
  for (int mi = 0; mi < 4; ++mi)
#pragma unroll
    for (int ni = 0; ni < 4; ++ni) {
      int row0 = base_c + mi * 16 + kg * 4;
      int col = wn * 64 + ni * 16 + m16;
#pragma unroll
      for (int r = 0; r < 4; ++r)
        dst[(size_t)(row0 + r) * 128 + col] = acc[mi][ni][r];
    }
}

// K1b: reduce split-K partials -> g [8192][128] f32
__global__ __launch_bounds__(256) void k1b_reduce(const float* __restrict__ part,
                                                  float* __restrict__ g, int np) {
  int idx = blockIdx.x * 256 + threadIdx.x;
  float s = 0.f;
  for (int p = 0; p < np; ++p) s += part[(size_t)p * 1048576 + idx];
  g[idx] = s;
}

// ---------------------------------------------------------------------------
// K2: mode mix + irfft coefficient prep -> Ah/Al bf16 [c][128]
// ---------------------------------------------------------------------------
__global__ __launch_bounds__(256) void k2_mix(const float* __restrict__ g,
                                              const float* __restrict__ wre,
                                              const float* __restrict__ wim,
                                              unsigned short* __restrict__ Ah,
                                              unsigned short* __restrict__ Al) {
  int oq = blockIdx.x;  // 16
  int h = blockIdx.y;   // 8
  int b = blockIdx.z;   // 16
  __shared__ float gre[64][64], gim[64][64];
  int t = threadIdx.x;
  int bh = b * 8 + h;
#pragma unroll
  for (int j = 0; j < 16; ++j) {
    int idx = j * 256 + t, ir = idx >> 6, mr = idx & 63;
    const float* row = &g[((size_t)bh * 64 + ir) * 128];
    gre[ir][mr] = row[mr];
    gim[ir][mr] = row[64 + mr];
  }
  __syncthreads();
  int o = oq * 4 + (t >> 6), m = t & 63;
  float are = 0.f, aim = 0.f;
  for (int i = 0; i < 64; ++i) {
    float gr = gre[i][m], gi = gim[i][m];
    int wofs = ((h * 64 + i) * 64 + o) * 64 + m;
    float wr = wre[wofs], wi = wim[wofs];
    are = fmaf(gr, wr, are);
    are = fmaf(-gi, wi, are);
    aim = fmaf(gr, wi, aim);
    aim = fmaf(gi, wr, aim);
  }
  const float invL = 1.0f / (float)L_FFT;
  float outre = are * ((m == 0) ? invL : 2.0f * invL);
  float outim = (m == 0) ? 0.0f : (-2.0f * invL) * aim;
  size_t base = ((size_t)bh * 64 + o) * 128;
  unsigned short h16, l16;
  split_bf16(outre, h16, l16);
  Ah[base + m] = h16; Al[base + m] = l16;
  split_bf16(outim, h16, l16);
  Ah[base + 64 + m] = h16; Al[base + 64 + m] = l16;
}

// ---------------------------------------------------------------------------
// K3: inverse GEMM via MFMA, zero LDS, pure streaming.
// y[c][l] = sum_k A[c][k] * T2[l][k];  block 128c x 128l, K=128 in 4 chunks.
// ---------------------------------------------------------------------------
__global__ __launch_bounds__(256) void k3_inverse(const unsigned short* __restrict__ Ah,
                                                  const unsigned short* __restrict__ Al,
                                                  const unsigned short* __restrict__ T2h,
                                                  const unsigned short* __restrict__ T2l,
                                                  float* __restrict__ y) {
  int ltile = blockIdx.x;   // 0..31
  int c0 = blockIdx.y * 128;
  int t = threadIdx.x;
  int wave = t >> 6, lane = t & 63;
  int wm = wave >> 1, wn = wave & 1;
  int m16 = lane & 15, kg = lane >> 4;

  f32x4 acc[4][4] = {};

#pragma unroll
  for (int kk = 0; kk < 128; kk += 32) {
    bf16x8 bhf[4], blf[4];
#pragma unroll
    for (int ni = 0; ni < 4; ++ni) {
      int l = ltile * 128 + wn * 64 + ni * 16 + m16;
      size_t off = (size_t)l * 128 + kk + kg * 8;
      bhf[ni] = *(const bf16x8*)(T2h + off);
      blf[ni] = *(const bf16x8*)(T2l + off);
    }
#pragma unroll
    for (int mi = 0; mi < 4; ++mi) {
      int c = c0 + wm * 64 + mi * 16 + m16;
      size_t off = (size_t)c * 128 + kk + kg * 8;
      bf16x8 ah = *(const bf16x8*)(Ah + off);
      bf16x8 al = *(const bf16x8*)(Al + off);
#pragma unroll
      for (int ni = 0; ni < 4; ++ni) {
        acc[mi][ni] = __builtin_amdgcn_mfma_f32_16x16x32_bf16(ah, bhf[ni], acc[mi][ni], 0, 0, 0);
        acc[mi][ni] = __builtin_amdgcn_mfma_f32_16x16x32_bf16(ah, blf[ni], acc[mi][ni], 0, 0, 0);
        acc[mi][ni] = __builtin_amdgcn_mfma_f32_16x16x32_bf16(al, bhf[ni], acc[mi][ni], 0, 0, 0);
      }
    }
  }

#pragma unroll
  for (int mi = 0; mi < 4; ++mi)
#pragma unroll
    for (int ni = 0; ni < 4; ++ni) {
      int row0 = c0 + wm * 64 + mi * 16 + kg * 4;
      int col = ltile * 128 + wn * 64 + ni * 16 + m16;
#pragma unroll
      for (int r = 0; r < 4; ++r)
        y[(size_t)(row0 + r) * L_FFT + col] = acc[mi][ni][r];
    }
}

// ---------------------------------------------------------------------------
extern "C" void kernel_launch(void* const* d_in, const int* in_sizes, int n_in,
                              void* d_out, int out_size, void* d_ws, size_t ws_size,
                              hipStream_t stream) {
  const float* q   = (const float*)d_in[0];
  const float* wre = (const float*)d_in[4];
  const float* wim = (const float*)d_in[5];
  const int* index = (const int*)d_in[6];
  float* y = (float*)d_out;
  char* ws = (char*)d_ws;

  // byte layout: T1h 1MB | T1l 1MB | T2h 1MB | T2l 1MB | Ah 2MB | Al 2MB | g 4MB | part np*4MB
  unsigned short* T1h = (unsigned short*)(ws);
  unsigned short* T1l = (unsigned short*)(ws + (1u << 20));
  unsigned short* T2h = (unsigned short*)(ws + (2u << 20));
  unsigned short* T2l = (unsigned short*)(ws + (3u << 20));
  unsigned short* Ah  = (unsigned short*)(ws + (4u << 20));
  unsigned short* Al  = (unsigned short*)(ws + (6u << 20));
  float* g            = (float*)(ws + (8u << 20));
  const size_t base_bytes = 12u << 20;

  int np = 1;
  while (np < 16) {
    size_t need = base_bytes + (size_t)(np * 2) * (4u << 20);
    if (need <= ws_size) np *= 2; else break;
  }
  float* part = (np == 1) ? g : (float*)(ws + base_bytes);
  int kspan = L_FFT / np;

  k0_tables<<<dim3(2048), dim3(256), 0, stream>>>(index, T1h, T1l, T2h, T2l);
  k1_forward<<<dim3(64, np), dim3(256), 0, stream>>>(q, T1h, T1l, part, kspan);
  if (np > 1)
    k1b_reduce<<<dim3(4096), dim3(256), 0, stream>>>(part, g, np);
  k2_mix<<<dim3(16, 8, 16), dim3(256), 0, stream>>>(g, wre, wim, Ah, Al);
  k3_inverse<<<dim3(32, 64), dim3(256), 0, stream>>>(Ah, Al, T2h, T2l, y);
}

// Round 3
// 114.389 us; speedup vs baseline: 2.4181x; 2.4181x over previous
//
#include <hip/hip_runtime.h>

#define L_FFT 4096
#define NCH 512

typedef __attribute__((ext_vector_type(8))) short bf16x8;
typedef __attribute__((ext_vector_type(4))) float f32x4;

__device__ __forceinline__ void split_bf16(float x, unsigned short& h, unsigned short& l) {
  unsigned u = __float_as_uint(x);
  h = (unsigned short)(u >> 16);                    // truncate -> hi
  float fh = __uint_as_float(u & 0xffff0000u);
  float lo = x - fh;                                // exact residual
  l = (unsigned short)(__float_as_uint(lo) >> 16);  // truncate -> lo
}

// ---------------------------------------------------------------------------
// k0a: phase tables ctab/stab[4096] = cos/sin(2*pi*ph/4096)
// ---------------------------------------------------------------------------
__global__ __launch_bounds__(256) void k0a_phase(float* __restrict__ ctab,
                                                 float* __restrict__ stab) {
  int i = blockIdx.x * 256 + threadIdx.x;  // 0..4095
  float s, c;
  sincosf(6.2831853071795864769f / 4096.f * (float)i, &s, &c);
  ctab[i] = c;
  stab[i] = s;
}

// ---------------------------------------------------------------------------
// k0b: expand phase tables into MFMA-fragment-swizzled bf16 hi/lo tables.
// T1f (forward B): idx = ((chunk*2+wn)*4+ni)*512 + lane*8 + i
//   kcol = wn*64+ni*16+(lane&15), l = chunk*32+(lane>>4)*8+i
//   val  = kcol<64 ?  cos(w0*l*index[kcol]) : -sin(w0*l*index[kcol-64])
// T2f (inverse B): idx = (lt16*4+kc2)*512 + lane*8 + i
//   l = lt16*16+(lane&15), k = kc2*32+(lane>>4)*8+i
//   val  = k<64 ? cos(w0*l*k) : sin(w0*l*(k-64))
// ---------------------------------------------------------------------------
__global__ __launch_bounds__(256) void k0b_expand(const int* __restrict__ index,
                                                  const float* __restrict__ ctab,
                                                  const float* __restrict__ stab,
                                                  unsigned short* __restrict__ T1fh,
                                                  unsigned short* __restrict__ T1fl,
                                                  unsigned short* __restrict__ T2fh,
                                                  unsigned short* __restrict__ T2fl) {
  int idx = blockIdx.x * 256 + threadIdx.x;  // 0..524287
  int i = idx & 7, lane = (idx >> 3) & 63;
  int m16 = lane & 15, kg = lane >> 4;
  {
    int ni = (idx >> 9) & 3, wn = (idx >> 11) & 1, chunk = idx >> 12;
    int kcol = wn * 64 + ni * 16 + m16;
    int l = chunk * 32 + kg * 8 + i;
    int f = index[kcol & 63];
    int ph = (l * f) & 4095;
    float v = (kcol < 64) ? ctab[ph] : -stab[ph];
    unsigned short h, lo;
    split_bf16(v, h, lo);
    T1fh[idx] = h;
    T1fl[idx] = lo;
  }
  {
    int kc2 = (idx >> 9) & 3, lt16 = idx >> 11;
    int l = lt16 * 16 + m16;
    int k = kc2 * 32 + kg * 8 + i;
    int ph = (l * (k & 63)) & 4095;
    float v = (k < 64) ? ctab[ph] : stab[ph];
    unsigned short h, lo;
    split_bf16(v, h, lo);
    T2fh[idx] = h;
    T2fl[idx] = lo;
  }
}

// ---------------------------------------------------------------------------
// k1: forward GEMM, zero LDS.  part[p][c][k] = sum_l X[c,l]*T1[k,l]
// Block 128c x 128k, 4 waves (each 64x64 as 4x4 of 16x16x32), K-chunk 32.
// A: 8 stride-2KB dwords/fragment direct from q, hi/lo split in regs.
// B: contiguous 16B/lane loads from pre-swizzled T1f.
// ---------------------------------------------------------------------------
__global__ __launch_bounds__(256) void k1_forward(const float* __restrict__ q,
                                                  const unsigned short* __restrict__ T1fh,
                                                  const unsigned short* __restrict__ T1fl,
                                                  float* __restrict__ part,
                                                  int kspan) {
  int ctile = blockIdx.x;  // 0..63
  int p = blockIdx.y;
  int b = ctile >> 2, ch0 = (ctile & 3) * 128;
  int t = threadIdx.x, wave = t >> 6, lane = t & 63;
  int wm = wave >> 1, wn = wave & 1, m16 = lane & 15, kg = lane >> 4;
  int l0 = p * kspan;

  f32x4 acc[4][4] = {};

  for (int cc = 0; cc < kspan; cc += 32) {
    int chunk = (l0 + cc) >> 5;
    bf16x8 bh[4], bl[4];
#pragma unroll
    for (int ni = 0; ni < 4; ++ni) {
      size_t off = ((size_t)((chunk * 2 + wn) * 4 + ni) << 9) + lane * 8;
      bh[ni] = *(const bf16x8*)(T1fh + off);
      bl[ni] = *(const bf16x8*)(T1fl + off);
    }
#pragma unroll
    for (int mi = 0; mi < 4; ++mi) {
      int c = ch0 + wm * 64 + mi * 16 + m16;
      const float* qp = q + (size_t)(b * L_FFT + l0 + cc + kg * 8) * NCH + c;
      float xf[8];
#pragma unroll
      for (int i = 0; i < 8; ++i) xf[i] = qp[(size_t)i * NCH];
      unsigned uh[8], ul[8];
#pragma unroll
      for (int i = 0; i < 8; ++i) {
        unsigned u = __float_as_uint(xf[i]);
        uh[i] = u;
        float fh = __uint_as_float(u & 0xffff0000u);
        ul[i] = __float_as_uint(xf[i] - fh);
      }
      union { bf16x8 v; unsigned w[4]; } ah, al;
#pragma unroll
      for (int j = 0; j < 4; ++j) {
        ah.w[j] = (uh[2 * j] >> 16) | (uh[2 * j + 1] & 0xffff0000u);
        al.w[j] = (ul[2 * j] >> 16) | (ul[2 * j + 1] & 0xffff0000u);
      }
#pragma unroll
      for (int ni = 0; ni < 4; ++ni) {
        acc[mi][ni] = __builtin_amdgcn_mfma_f32_16x16x32_bf16(ah.v, bh[ni], acc[mi][ni], 0, 0, 0);
        acc[mi][ni] = __builtin_amdgcn_mfma_f32_16x16x32_bf16(ah.v, bl[ni], acc[mi][ni], 0, 0, 0);
        acc[mi][ni] = __builtin_amdgcn_mfma_f32_16x16x32_bf16(al.v, bh[ni], acc[mi][ni], 0, 0, 0);
      }
    }
  }

  int base_c = ctile * 128 + wm * 64;
  float* dst = part + (size_t)p * 1048576;
#pragma unroll
  for (int mi = 0; mi < 4; ++mi)
#pragma unroll
    for (int ni = 0; ni < 4; ++ni) {
      int row0 = base_c + mi * 16 + kg * 4;
      int col = wn * 64 + ni * 16 + m16;
#pragma unroll
      for (int r = 0; r < 4; ++r)
        dst[(size_t)(row0 + r) * 128 + col] = acc[mi][ni][r];
    }
}

// k1b: reduce split-K partials -> g [8192][128] f32
__global__ __launch_bounds__(256) void k1b_reduce(const float* __restrict__ part,
                                                  float* __restrict__ g, int np) {
  int idx = blockIdx.x * 256 + threadIdx.x;
  float s = 0.f;
  for (int p = 0; p < np; ++p) s += part[(size_t)p * 1048576 + idx];
  g[idx] = s;
}

// ---------------------------------------------------------------------------
// k2: mode mix + irfft coefficient prep -> Afh/Afl bf16, k3-fragment-swizzled.
// afidx(c,k) = (((c>>4)*4+(k>>5))*64 + ((k>>3)&3)*16 + (c&15))*8 + (k&7)
// ---------------------------------------------------------------------------
__global__ __launch_bounds__(256) void k2_mix(const float* __restrict__ g,
                                              const float* __restrict__ wre,
                                              const float* __restrict__ wim,
                                              unsigned short* __restrict__ Afh,
                                              unsigned short* __restrict__ Afl) {
  int oq = blockIdx.x;  // 16
  int h = blockIdx.y;   // 8
  int b = blockIdx.z;   // 16
  __shared__ float gre[64][64], gim[64][64];
  int t = threadIdx.x;
  int bh = b * 8 + h;
#pragma unroll
  for (int j = 0; j < 16; ++j) {
    int idx = j * 256 + t, ir = idx >> 6, mr = idx & 63;
    const float* row = &g[((size_t)bh * 64 + ir) * 128];
    gre[ir][mr] = row[mr];
    gim[ir][mr] = row[64 + mr];
  }
  __syncthreads();
  int o = oq * 4 + (t >> 6), m = t & 63;
  float are = 0.f, aim = 0.f;
  for (int i = 0; i < 64; ++i) {
    float gr = gre[i][m], gi = gim[i][m];
    int wofs = ((h * 64 + i) * 64 + o) * 64 + m;
    float wr = wre[wofs], wi = wim[wofs];
    are = fmaf(gr, wr, are);
    are = fmaf(-gi, wi, are);
    aim = fmaf(gr, wi, aim);
    aim = fmaf(gi, wr, aim);
  }
  const float invL = 1.0f / (float)L_FFT;
  float outre = are * ((m == 0) ? invL : 2.0f * invL);
  float outim = (m == 0) ? 0.0f : (-2.0f * invL) * aim;
  int c = bh * 64 + o;
  unsigned short h16, l16;
  {
    int k = m;
    int afidx = (((c >> 4) * 4 + (k >> 5)) * 64 + ((k >> 3) & 3) * 16 + (c & 15)) * 8 + (k & 7);
    split_bf16(outre, h16, l16);
    Afh[afidx] = h16;
    Afl[afidx] = l16;
  }
  {
    int k = 64 + m;
    int afidx = (((c >> 4) * 4 + (k >> 5)) * 64 + ((k >> 3) & 3) * 16 + (c & 15)) * 8 + (k & 7);
    split_bf16(outim, h16, l16);
    Afh[afidx] = h16;
    Afl[afidx] = l16;
  }
}

// ---------------------------------------------------------------------------
// k3: inverse GEMM, zero LDS, all operands fragment-swizzled & coalesced.
// y[c][l] = sum_k A[c][k] * T2[l][k]; block 128c x 128l, K=128 in 4 chunks.
// ---------------------------------------------------------------------------
__global__ __launch_bounds__(256) void k3_inverse(const unsigned short* __restrict__ Afh,
                                                  const unsigned short* __restrict__ Afl,
                                                  const unsigned short* __restrict__ T2fh,
                                                  const unsigned short* __restrict__ T2fl,
                                                  float* __restrict__ y) {
  int ltile = blockIdx.x;   // 0..31
  int c0 = blockIdx.y * 128;
  int t = threadIdx.x, wave = t >> 6, lane = t & 63;
  int wm = wave >> 1, wn = wave & 1, m16 = lane & 15, kg = lane >> 4;

  f32x4 acc[4][4] = {};

#pragma unroll
  for (int kc2 = 0; kc2 < 4; ++kc2) {
    bf16x8 bh[4], bl[4];
#pragma unroll
    for (int ni = 0; ni < 4; ++ni) {
      size_t off = ((size_t)((ltile * 8 + wn * 4 + ni) * 4 + kc2) << 9) + lane * 8;
      bh[ni] = *(const bf16x8*)(T2fh + off);
      bl[ni] = *(const bf16x8*)(T2fl + off);
    }
#pragma unroll
    for (int mi = 0; mi < 4; ++mi) {
      int c16 = (c0 >> 4) + wm * 4 + mi;
      size_t off = ((size_t)(c16 * 4 + kc2) << 9) + lane * 8;
      bf16x8 ah = *(const bf16x8*)(Afh + off);
      bf16x8 al = *(const bf16x8*)(Afl + off);
#pragma unroll
      for (int ni = 0; ni < 4; ++ni) {
        acc[mi][ni] = __builtin_amdgcn_mfma_f32_16x16x32_bf16(ah, bh[ni], acc[mi][ni], 0, 0, 0);
        acc[mi][ni] = __builtin_amdgcn_mfma_f32_16x16x32_bf16(ah, bl[ni], acc[mi][ni], 0, 0, 0);
        acc[mi][ni] = __builtin_amdgcn_mfma_f32_16x16x32_bf16(al, bh[ni], acc[mi][ni], 0, 0, 0);
      }
    }
  }

#pragma unroll
  for (int mi = 0; mi < 4; ++mi)
#pragma unroll
    for (int ni = 0; ni < 4; ++ni) {
      int row0 = c0 + wm * 64 + mi * 16 + kg * 4;
      int col = ltile * 128 + wn * 64 + ni * 16 + m16;
#pragma unroll
      for (int r = 0; r < 4; ++r)
        __builtin_nontemporal_store(acc[mi][ni][r],
                                    &y[(size_t)(row0 + r) * L_FFT + col]);
    }
}

// ---------------------------------------------------------------------------
extern "C" void kernel_launch(void* const* d_in, const int* in_sizes, int n_in,
                              void* d_out, int out_size, void* d_ws, size_t ws_size,
                              hipStream_t stream) {
  const float* q   = (const float*)d_in[0];
  const float* wre = (const float*)d_in[4];
  const float* wim = (const float*)d_in[5];
  const int* index = (const int*)d_in[6];
  float* y = (float*)d_out;
  char* ws = (char*)d_ws;

  // byte layout:
  // T1fh 1MB | T1fl 1MB | T2fh 1MB | T2fl 1MB | Afh 2MB | Afl 2MB | g 4MB |
  // ctab 16KB | stab 16KB | part np*4MB (at 13MB)
  unsigned short* T1fh = (unsigned short*)(ws);
  unsigned short* T1fl = (unsigned short*)(ws + (1u << 20));
  unsigned short* T2fh = (unsigned short*)(ws + (2u << 20));
  unsigned short* T2fl = (unsigned short*)(ws + (3u << 20));
  unsigned short* Afh  = (unsigned short*)(ws + (4u << 20));
  unsigned short* Afl  = (unsigned short*)(ws + (6u << 20));
  float* g             = (float*)(ws + (8u << 20));
  float* ctab          = (float*)(ws + (12u << 20));
  float* stab          = (float*)(ws + (12u << 20) + 16384);
  float* part          = (float*)(ws + (13u << 20));

  int np = 1;
  while (np < 8) {
    size_t need = (13u << 20) + (size_t)(np * 2) * (4u << 20);
    if (need <= ws_size) np *= 2; else break;
  }
  if ((13u << 20) + (size_t)np * (4u << 20) > ws_size) { np = 1; part = g; }
  int kspan = L_FFT / np;

  k0a_phase<<<dim3(16), dim3(256), 0, stream>>>(ctab, stab);
  k0b_expand<<<dim3(2048), dim3(256), 0, stream>>>(index, ctab, stab,
                                                   T1fh, T1fl, T2fh, T2fl);
  k1_forward<<<dim3(64, np), dim3(256), 0, stream>>>(q, T1fh, T1fl, part, kspan);
  if (np > 1)
    k1b_reduce<<<dim3(4096), dim3(256), 0, stream>>>(part, g, np);
  k2_mix<<<dim3(16, 8, 16), dim3(256), 0, stream>>>(g, wre, wim, Afh, Afl);
  k3_inverse<<<dim3(32, 64), dim3(256), 0, stream>>>(Afh, Afl, T2fh, T2fl, y);
}